// Round 5
// baseline (939.986 us; speedup 1.0000x reference)
//
#include <hip/hip_runtime.h>
#include <stdint.h>
#include <math.h>

#define K_CODES 4096
#define DIM 128
#define N_FLAT 32768      // 32 * 32 * 32
#define HW 1024           // 32*32 spatial per batch

// output offsets (floats): quantized_st, loss, perplexity, encodings, indices
#define OFF_Q    0
#define OFF_LOSS 4194304
#define OFF_PERP 4194305
#define OFF_ENC  4194306
#define OFF_IDX  138412034

// workspace offsets (bytes)
#define WS_PACKED 0                        // 32768 * 8
#define WS_COUNTS 262144                   // 4096 * 4
#define WS_WSQ    278528                   // 4096 * 4
#define WS_XSQ    294912                   // 32768 * 4
#define WS_PART   425984                   // 1024 * 4
#define WS_XHL    430080                   // 32768 rows * 256 f16 = 16 MB
#define WS_WHL    (WS_XHL + 16777216)      // 4096 rows * 256 f16 = 2 MB

typedef _Float16 f16x8 __attribute__((ext_vector_type(8)));
typedef float    f32x4 __attribute__((ext_vector_type(4)));

// f16 plane rows: [row][0:128]=h, [row][128:256]=l (512 B). Exact pow2
// scales x*32, w*1024 -> acc = 2^15*dot, unscale by 2^-14 is exact.

// ---------------- K1: w_sq + counts zero. grid 1024 x 256 (4 waves = 4 k) --
__global__ __launch_bounds__(256) void wsq_kernel(const float* __restrict__ w,
                                                  float* __restrict__ wsq,
                                                  float* __restrict__ counts) {
    int wave = threadIdx.x >> 6, lane = threadIdx.x & 63;
    int k = blockIdx.x * 4 + wave;
    float a = w[k * DIM + lane];
    float b = w[k * DIM + lane + 64];
    float s = a * a + b * b;
    #pragma unroll
    for (int o = 32; o > 0; o >>= 1) s += __shfl_down(s, o, 64);
    if (lane == 0) { wsq[k] = s; counts[k] = 0.f; }
}

// ---------------- K2: w -> f16 h/l planes ----------------------------------
__global__ __launch_bounds__(256) void wplanes_kernel(const float* __restrict__ w,
                                                      _Float16* __restrict__ whl) {
    int T = blockIdx.x * 256 + threadIdx.x;
    int k = T >> 2, seg = T & 3;
    const float* wp = w + (size_t)k * DIM + seg * 32;
    _Float16* row = whl + (size_t)k * 256;
    #pragma unroll
    for (int q = 0; q < 4; ++q) {
        float4 a = *(const float4*)(wp + q * 8);
        float4 b = *(const float4*)(wp + q * 8 + 4);
        float vv[8] = {a.x, a.y, a.z, a.w, b.x, b.y, b.z, b.w};
        f16x8 hv, lv;
        #pragma unroll
        for (int j = 0; j < 8; ++j) {
            float v = 1024.0f * vv[j];
            _Float16 h = (_Float16)v;
            _Float16 l = (_Float16)(v - (float)h);
            hv[j] = h; lv[j] = l;
        }
        *(f16x8*)(row + seg * 32 + q * 8) = hv;
        *(f16x8*)(row + 128 + seg * 32 + q * 8) = lv;
    }
}

// ---------------- K3: x -> planes + x_sq + packed init (fused) -------------
__global__ __launch_bounds__(256) void xprep_kernel(const float* __restrict__ x,
                                                    _Float16* __restrict__ xhl,
                                                    float* __restrict__ xsq,
                                                    unsigned long long* __restrict__ packed) {
    __shared__ float xt[128 * 65];            // [c][n], pad 65
    const int t = threadIdx.x;
    const int n0 = blockIdx.x * 64;
    const int b = n0 >> 10, hw0 = n0 & 1023;
    const float* xg = x + (size_t)b * (DIM * HW) + hw0;
    #pragma unroll
    for (int i = 0; i < 16; ++i) {
        int idx = i * 256 + t;                // 4096 float2
        int c = idx >> 5, n2 = (idx & 31) << 1;
        float2 v = *(const float2*)(xg + c * HW + n2);
        xt[c * 65 + n2] = v.x;
        xt[c * 65 + n2 + 1] = v.y;
    }
    __syncthreads();
    if (t < 64) {
        packed[n0 + t] = ~0ull;
        float s = 0.f;                        // strict c order, fp32 (== ref path)
        #pragma unroll
        for (int c = 0; c < DIM; ++c) {
            float v = xt[c * 65 + t];
            s = fmaf(v, v, s);
        }
        xsq[n0 + t] = s;
    }
    const int n = t >> 2, seg = t & 3;
    _Float16* row = xhl + (size_t)(n0 + n) * 256;
    #pragma unroll
    for (int q = 0; q < 4; ++q) {
        f16x8 hv, lv;
        #pragma unroll
        for (int j = 0; j < 8; ++j) {
            float v = 32.0f * xt[(seg * 32 + q * 8 + j) * 65 + n];
            _Float16 h = (_Float16)v;
            _Float16 l = (_Float16)(v - (float)h);
            hv[j] = h; lv[j] = l;
        }
        *(f16x8*)(row + seg * 32 + q * 8) = hv;
        *(f16x8*)(row + 128 + seg * 32 + q * 8) = lv;
    }
}

// ---------------- K4: MFMA distance GEMM + deferred split-K argmin ---------
// grid (256 n-tiles, 8 k-supertiles), block 256 = 4 waves 2x2. Each block:
// 128n x 512k via 4 ks sub-tiles x 4 c0 chunks. Wave tile 64x64 = 4x4
// mfma_f32_16x16x32_f16, 3 MFMAs per tile (hH,hL,lH Dekker split).
// R5 restructure (R4 post-mortem: LDS pipe ~1500 cyc/CU-step vs MFMA 480
// -> LDS-throughput-bound; memsetAsync serialized 85us):
//  (a) X staged ONCE into 64 KB XOR-swizzled LDS (byte ^= (row&7)<<4,
//      ~2-way conflicts = free). ONE barrier total. X global traffic
//      512->128 MB; zero ds_writes in loop.
//  (b) W fragments read per-lane straight from L2 (whl = 2 MB, resident);
//      register double-buffered one step ahead (static A/B sets). NO
//      barriers in the main loop; VMEM pipe does W while LDS does X.
//  (c) enc zero-fill back INSIDE K4 (R3 addressing, proven absmax 0);
//      with no barriers the stores never force a vmcnt(0) drain.
//  (d) launch_bounds(256,2): VGPR cap 256 (est ~185 live), 2 blocks/CU.
//  Numerics bit-identical to R3/R4: same MFMA order, same packed-u64
//  argmin/tie-break, same epilogue.
__global__ __launch_bounds__(256, 2) void dist_argmin(
    const _Float16* __restrict__ xhl, const _Float16* __restrict__ whl,
    const float* __restrict__ wsq, const float* __restrict__ xsq,
    unsigned long long* __restrict__ packed, float* __restrict__ enc)
{
    __shared__ __align__(16) char xs[128 * 512];      // X tile, swizzled
    __shared__ float xsq_s[128];
    __shared__ unsigned long long red[128];

    const int tid  = threadIdx.x;
    const int lane = tid & 63, wave = tid >> 6;
    const int lq   = lane & 15, quad = lane >> 4;
    const int wn0  = (wave >> 1) * 64, wk0 = (wave & 1) * 64;
    const int n0   = blockIdx.x * 128;
    const int kbase = blockIdx.y * 512;
    const int swz  = (lq & 7) << 4;                   // row&7 == lq&7 for frag rows

    float* ebase = enc + (size_t)n0 * K_CODES + kbase;
    float* efill = ebase + (size_t)(tid >> 7) * K_CODES + 2 + (tid & 127) * 4;

    if (tid < 128) {
        float2 z2; z2.x = 0.f; z2.y = 0.f;
        *(float2*)(ebase + (size_t)tid * K_CODES) = z2;   // head cols 0..1
        xsq_s[tid] = xsq[n0 + tid];
        red[tid] = ~0ull;
    }

    // ---- stage X tile (64 KB) into swizzled LDS, one time ----------------
    const _Float16* xbase = xhl + (size_t)n0 * 256;
    #pragma unroll
    for (int i = 0; i < 16; ++i) {
        int idx = i * 256 + tid;              // 16B chunk index, 0..4095
        int r  = idx >> 5;                    // row 0..127
        int bc = (idx & 31) << 4;             // byte col 0..496
        f16x8 v = *(const f16x8*)(xbase + idx * 8);
        *(f16x8*)(xs + r * 512 + (bc ^ ((r & 7) << 4))) = v;
    }
    __syncthreads();   // the ONLY barrier before the final reduce

    // per-lane W row pointer: row (kbase + wk0 + lq), col quad*8
    const _Float16* wrow = whl + (size_t)(kbase + wk0 + lq) * 256 + quad * 8;
    // per-lane X frag row byte bases
    int rowb[4];
    #pragma unroll
    for (int i = 0; i < 4; ++i) rowb[i] = (wn0 + i * 16 + lq) * 512;

    f32x4 acc[4][4];
    float wk[4];
    f16x8 bhA[4], blA[4], bhB[4], blB[4];

    // prologue: W frags for (ks=0, c0=0) into set A
    #pragma unroll
    for (int ki = 0; ki < 4; ++ki) {
        bhA[ki] = *(const f16x8*)(wrow + ki * 4096);
        blA[ki] = *(const f16x8*)(wrow + ki * 4096 + 128);
    }

// one (ks,c0) step: read X frags (LDS), prefetch next W (L2), enc-fill 4
// stores, 48 MFMAs on current W set. PRE=0 skips prefetch (last step).
#define STEP(ks_, c0_, CH, CL, PRE, PH, PL, preoff_)                          \
    do {                                                                       \
        f16x8 ah[4], al[4];                                                    \
        _Pragma("unroll")                                                      \
        for (int i = 0; i < 4; ++i) {                                          \
            int cb = (c0_) * 64 + quad * 16;                                   \
            ah[i] = *(const f16x8*)(xs + rowb[i] + (cb ^ swz));                \
            al[i] = *(const f16x8*)(xs + rowb[i] + 256 + (cb ^ swz));          \
        }                                                                      \
        if (PRE) {                                                             \
            _Pragma("unroll")                                                  \
            for (int ki = 0; ki < 4; ++ki) {                                   \
                PH[ki] = *(const f16x8*)(wrow + (preoff_) + ki * 4096);        \
                PL[ki] = *(const f16x8*)(wrow + (preoff_) + ki * 4096 + 128);  \
            }                                                                  \
        }                                                                      \
        {                                                                      \
            float4 z4; z4.x = z4.y = z4.z = z4.w = 0.f;                        \
            const int s_ = (ks_) * 4 + (c0_);                                  \
            _Pragma("unroll")                                                  \
            for (int j = 0; j < 4; ++j)                                        \
                *(float4*)(efill + (size_t)(s_ * 8 + j * 2) * K_CODES) = z4;   \
        }                                                                      \
        _Pragma("unroll")                                                      \
        for (int ki = 0; ki < 4; ++ki)                                         \
            _Pragma("unroll")                                                  \
            for (int ni = 0; ni < 4; ++ni) {                                   \
                acc[ni][ki] = __builtin_amdgcn_mfma_f32_16x16x32_f16(          \
                    ah[ni], CH[ki], acc[ni][ki], 0, 0, 0);                     \
                acc[ni][ki] = __builtin_amdgcn_mfma_f32_16x16x32_f16(          \
                    ah[ni], CL[ki], acc[ni][ki], 0, 0, 0);                     \
                acc[ni][ki] = __builtin_amdgcn_mfma_f32_16x16x32_f16(          \
                    al[ni], CH[ki], acc[ni][ki], 0, 0, 0);                     \
            }                                                                  \
    } while (0)

    for (int ks = 0; ks < 4; ++ks) {
        const int k0 = kbase + ks * 128;
        #pragma unroll
        for (int ki = 0; ki < 4; ++ki)
            wk[ki] = wsq[k0 + wk0 + ki * 16 + lq];
        #pragma unroll
        for (int i = 0; i < 4; ++i)
            #pragma unroll
            for (int j = 0; j < 4; ++j)
                acc[i][j] = (f32x4){0.f, 0.f, 0.f, 0.f};

        const int wko = ks * 32768;   // f16 offset of this ks within wrow

        STEP(ks, 0, bhA, blA, 1, bhB, blB, wko + 32);
        STEP(ks, 1, bhB, blB, 1, bhA, blA, wko + 64);
        STEP(ks, 2, bhA, blA, 1, bhB, blB, wko + 96);
        if (ks < 3) STEP(ks, 3, bhB, blB, 1, bhA, blA, wko + 32768);
        else        STEP(ks, 3, bhB, blB, 0, bhA, blA, 0);

        // ---- per-ks epilogue: distances + argmin -> LDS red[] -------------
        #pragma unroll
        for (int ni = 0; ni < 4; ++ni) {
            #pragma unroll
            for (int rg = 0; rg < 4; ++rg) {
                int rowl = wn0 + ni * 16 + quad * 4 + rg;
                float xr = xsq_s[rowl];
                float best = 3.4e38f; int bk = 0;
                #pragma unroll
                for (int ki = 0; ki < 4; ++ki) {
                    int kl = wk0 + ki * 16 + lq;
                    float t = xr - acc[ni][ki][rg] * 6.103515625e-05f; // 2^-14
                    t += wk[ki];
                    t += 1e-8f;
                    if (t < best) { best = t; bk = k0 + kl; }
                }
                unsigned u = __float_as_uint(best);
                u = (u & 0x80000000u) ? ~u : (u | 0x80000000u);
                unsigned long long pck =
                    ((unsigned long long)u << 32) | (unsigned)bk;
                #pragma unroll
                for (int m = 1; m < 16; m <<= 1) {
                    unsigned long long o = __shfl_xor(pck, m, 64);
                    if (o < pck) pck = o;
                }
                if (lq == 0) atomicMin(&red[rowl], pck);
            }
        }
    }
#undef STEP

    __syncthreads();
    if (tid < 128) atomicMin(&packed[n0 + tid], red[tid]);
}

// ---------------- K5: combine -> indices, one-hot 1.0, counts ---------------
__global__ __launch_bounds__(256) void combine(
    const unsigned long long* __restrict__ packed,
    float* __restrict__ idxf, float* __restrict__ enc,
    float* __restrict__ counts)
{
    int n = blockIdx.x * 256 + threadIdx.x;
    unsigned k = (unsigned)(packed[n] & 0xFFFFFFFFu);
    idxf[n] = (float)k;
    enc[(size_t)n * K_CODES + k] = 1.0f;
    atomicAdd(&counts[k], 1.0f);
}

// ---------------- K6: gather -> quantized_st (NCHW) + per-block loss partial
__global__ __launch_bounds__(256) void quantize_loss(
    const float* __restrict__ x, const float* __restrict__ w,
    const float* __restrict__ idxf, float* __restrict__ outq,
    float* __restrict__ part)
{
    const int base4 = (blockIdx.x * 256 + threadIdx.x) * 4;
    float s = 0.f;
    #pragma unroll
    for (int i = 0; i < 4; ++i) {
        int e  = base4 + i * 1048576;      // NCHW element index (x4 aligned)
        int hw = e & 1023;
        int c  = (e >> 10) & 127;
        int b  = e >> 17;
        int n  = (b << 10) | hw;           // multiple of 4
        float4 xv = *(const float4*)(x + e);
        float4 kf = *(const float4*)(idxf + n);
        float q0 = w[(int)kf.x * DIM + c];
        float q1 = w[(int)kf.y * DIM + c];
        float q2 = w[(int)kf.z * DIM + c];
        float q3 = w[(int)kf.w * DIM + c];
        float4 df; df.x = q0 - xv.x; df.y = q1 - xv.y;
                   df.z = q2 - xv.z; df.w = q3 - xv.w;
        float4 o;  o.x = xv.x + df.x; o.y = xv.y + df.y;
                   o.z = xv.z + df.z; o.w = xv.w + df.w;
        *(float4*)(outq + e) = o;
        s = fmaf(df.x, df.x, s);
        s = fmaf(df.y, df.y, s);
        s = fmaf(df.z, df.z, s);
        s = fmaf(df.w, df.w, s);
    }
    #pragma unroll
    for (int o = 32; o > 0; o >>= 1) s += __shfl_down(s, o, 64);
    __shared__ float ls[4];
    if ((threadIdx.x & 63) == 0) ls[threadIdx.x >> 6] = s;
    __syncthreads();
    if (threadIdx.x == 0) part[blockIdx.x] = ls[0] + ls[1] + ls[2] + ls[3];
}

// ---------------- K7: loss (from partials) + perplexity ---------------------
__global__ __launch_bounds__(256) void finalize(
    const float* __restrict__ counts, const float* __restrict__ part,
    float* __restrict__ out)
{
    __shared__ float sh[512];
    float h = 0.f;
    for (int k = threadIdx.x; k < K_CODES; k += 256) {
        float p = counts[k] * (1.0f / N_FLAT);
        h += p * logf(p + 1e-10f);
    }
    float s = 0.f;
    for (int i = threadIdx.x; i < 1024; i += 256) s += part[i];
    sh[threadIdx.x] = h;
    sh[256 + threadIdx.x] = s;
    __syncthreads();
    #pragma unroll
    for (int st = 128; st > 0; st >>= 1) {
        if (threadIdx.x < st) {
            sh[threadIdx.x] += sh[threadIdx.x + st];
            sh[256 + threadIdx.x] += sh[256 + threadIdx.x + st];
        }
        __syncthreads();
    }
    if (threadIdx.x == 0) {
        float perp = expf(-sh[0]);
        float loss = 1.25f * (sh[256] / 4194304.0f);
        if (isnan(loss) || isinf(loss)) loss = 0.1f;
        out[OFF_LOSS] = loss;
        out[OFF_PERP] = perp;
    }
}

extern "C" void kernel_launch(void* const* d_in, const int* in_sizes, int n_in,
                              void* d_out, int out_size, void* d_ws, size_t ws_size,
                              hipStream_t stream) {
    const float* x = (const float*)d_in[0];   // [32,128,32,32] fp32 NCHW
    const float* w = (const float*)d_in[1];   // [4096,128] fp32
    float* out = (float*)d_out;
    char* ws = (char*)d_ws;

    unsigned long long* packed = (unsigned long long*)(ws + WS_PACKED);
    float* counts = (float*)(ws + WS_COUNTS);
    float* wsq    = (float*)(ws + WS_WSQ);
    float* xsq    = (float*)(ws + WS_XSQ);
    float* part   = (float*)(ws + WS_PART);
    _Float16* xhl = (_Float16*)(ws + WS_XHL);
    _Float16* whl = (_Float16*)(ws + WS_WHL);

    wsq_kernel<<<K_CODES / 4, 256, 0, stream>>>(w, wsq, counts);
    wplanes_kernel<<<K_CODES * 4 / 256, 256, 0, stream>>>(w, whl);
    xprep_kernel<<<N_FLAT / 64, 256, 0, stream>>>(x, xhl, xsq, packed);

    dim3 g2(256, 8);
    dist_argmin<<<g2, 256, 0, stream>>>(xhl, whl, wsq, xsq, packed,
                                        out + OFF_ENC);

    combine<<<N_FLAT / 256, 256, 0, stream>>>(packed, out + OFF_IDX,
                                              out + OFF_ENC, counts);

    quantize_loss<<<1024, 256, 0, stream>>>(x, w, out + OFF_IDX,
                                            out + OFF_Q, part);

    finalize<<<1, 256, 0, stream>>>(counts, part, out);
}

// Round 6
// 892.015 us; speedup vs baseline: 1.0538x; 1.0538x over previous
//
#include <hip/hip_runtime.h>
#include <stdint.h>
#include <math.h>

#define K_CODES 4096
#define DIM 128
#define N_FLAT 32768      // 32 * 32 * 32
#define HW 1024           // 32*32 spatial per batch

// output offsets (floats): quantized_st, loss, perplexity, encodings, indices
#define OFF_Q    0
#define OFF_LOSS 4194304
#define OFF_PERP 4194305
#define OFF_ENC  4194306
#define OFF_IDX  138412034

// workspace offsets (bytes)
#define WS_PACKED 0                        // (unused since R6)
#define WS_COUNTS 262144                   // 4096 * 4
#define WS_WSQ    278528                   // 4096 * 4
#define WS_XSQ    294912                   // 32768 * 4
#define WS_PART   425984                   // 1024 * 4
#define WS_XHL    430080                   // 32768 rows * 256 f16 = 16 MB
#define WS_WHL    (WS_XHL + 16777216)      // 4096 rows * 256 f16 = 2 MB

typedef _Float16 f16x8 __attribute__((ext_vector_type(8)));
typedef float    f32x4 __attribute__((ext_vector_type(4)));

// f16 plane rows: [row][0:128]=h, [row][128:256]=l (512 B). Exact pow2
// scales x*32, w*1024 -> acc = 2^15*dot, unscale by 2^-14 is exact.

// ---------------- K1: w_sq + counts zero. grid 1024 x 256 (4 waves = 4 k) --
__global__ __launch_bounds__(256) void wsq_kernel(const float* __restrict__ w,
                                                  float* __restrict__ wsq,
                                                  float* __restrict__ counts) {
    int wave = threadIdx.x >> 6, lane = threadIdx.x & 63;
    int k = blockIdx.x * 4 + wave;
    float a = w[k * DIM + lane];
    float b = w[k * DIM + lane + 64];
    float s = a * a + b * b;
    #pragma unroll
    for (int o = 32; o > 0; o >>= 1) s += __shfl_down(s, o, 64);
    if (lane == 0) { wsq[k] = s; counts[k] = 0.f; }
}

// ---------------- K2: w -> f16 h/l planes ----------------------------------
__global__ __launch_bounds__(256) void wplanes_kernel(const float* __restrict__ w,
                                                      _Float16* __restrict__ whl) {
    int T = blockIdx.x * 256 + threadIdx.x;
    int k = T >> 2, seg = T & 3;
    const float* wp = w + (size_t)k * DIM + seg * 32;
    _Float16* row = whl + (size_t)k * 256;
    #pragma unroll
    for (int q = 0; q < 4; ++q) {
        float4 a = *(const float4*)(wp + q * 8);
        float4 b = *(const float4*)(wp + q * 8 + 4);
        float vv[8] = {a.x, a.y, a.z, a.w, b.x, b.y, b.z, b.w};
        f16x8 hv, lv;
        #pragma unroll
        for (int j = 0; j < 8; ++j) {
            float v = 1024.0f * vv[j];
            _Float16 h = (_Float16)v;
            _Float16 l = (_Float16)(v - (float)h);
            hv[j] = h; lv[j] = l;
        }
        *(f16x8*)(row + seg * 32 + q * 8) = hv;
        *(f16x8*)(row + 128 + seg * 32 + q * 8) = lv;
    }
}

// ---------------- K3: x -> planes + x_sq (fused) ---------------------------
__global__ __launch_bounds__(256) void xprep_kernel(const float* __restrict__ x,
                                                    _Float16* __restrict__ xhl,
                                                    float* __restrict__ xsq) {
    __shared__ float xt[128 * 65];            // [c][n], pad 65
    const int t = threadIdx.x;
    const int n0 = blockIdx.x * 64;
    const int b = n0 >> 10, hw0 = n0 & 1023;
    const float* xg = x + (size_t)b * (DIM * HW) + hw0;
    #pragma unroll
    for (int i = 0; i < 16; ++i) {
        int idx = i * 256 + t;                // 4096 float2
        int c = idx >> 5, n2 = (idx & 31) << 1;
        float2 v = *(const float2*)(xg + c * HW + n2);
        xt[c * 65 + n2] = v.x;
        xt[c * 65 + n2 + 1] = v.y;
    }
    __syncthreads();
    if (t < 64) {
        float s = 0.f;                        // strict c order, fp32 (== ref path)
        #pragma unroll
        for (int c = 0; c < DIM; ++c) {
            float v = xt[c * 65 + t];
            s = fmaf(v, v, s);
        }
        xsq[n0 + t] = s;
    }
    const int n = t >> 2, seg = t & 3;
    _Float16* row = xhl + (size_t)(n0 + n) * 256;
    #pragma unroll
    for (int q = 0; q < 4; ++q) {
        f16x8 hv, lv;
        #pragma unroll
        for (int j = 0; j < 8; ++j) {
            float v = 32.0f * xt[(seg * 32 + q * 8 + j) * 65 + n];
            _Float16 h = (_Float16)v;
            _Float16 l = (_Float16)(v - (float)h);
            hv[j] = h; lv[j] = l;
        }
        *(f16x8*)(row + seg * 32 + q * 8) = hv;
        *(f16x8*)(row + 128 + seg * 32 + q * 8) = lv;
    }
}

// ---------------- K4 (R6): full-K per block, fused argmin+combine ----------
// grid 512 blocks x 256 thr (4 waves). Block owns 64 n-rows x ALL 4096 k
// (32 chunks of 128). Wave w covers k-col [w*32, w*32+32) of each chunk,
// ALL 64 rows: acc[4][2] (32 VGPR), W frags bh/bl[2] dbuf (32 VGPR),
// pbest[4][4] u64 (32 VGPR) -> ~180 live, no forced bound, no spill.
//  - X staged ONCE into 32 KB XOR-swizzled LDS (byte ^= (row&7)<<4); one
//    barrier; X HBM traffic 512->16 MB total.
//  - W per-lane from L2 (whl 2 MB resident), 1-deep A/B reg prefetch; NO
//    barriers in the main loop.
//  - enc zero-fill interleaved per chunk (rows own-block only; kc=31 tail
//    is a float2 so nothing spills cross-block/into idxf -> race-free).
//  - argmin fully block-local: per-chunk per-lane pbest update (strict <,
//    chunks ascending => first-min tie-break preserved); end: 16-lane
//    shuffle reduce + LDS u64 atomicMin + final barrier (drains zero
//    stores) then idxf/enc=1.0/counts writes (old K5 fused, kernel gone).
//  Numerics bit-identical per (n,k): same Dekker MFMA order (hH,hL,lH),
//  same c0-ascending accumulation, same t formula & packed tie-break.
__global__ __launch_bounds__(256) void dist_argmin(
    const _Float16* __restrict__ xhl, const _Float16* __restrict__ whl,
    const float* __restrict__ wsq, const float* __restrict__ xsq,
    float* __restrict__ idxf, float* __restrict__ enc,
    float* __restrict__ counts)
{
    __shared__ __align__(16) char xs[64 * 512];      // X tile, swizzled, 32 KB
    __shared__ float xsq_s[64];
    __shared__ unsigned long long red[64];

    const int tid  = threadIdx.x;
    const int lane = tid & 63, wave = tid >> 6;
    const int lq   = lane & 15, quad = lane >> 4;
    const int wk0  = wave * 32;              // k offset within 128-chunk
    const int n0   = blockIdx.x * 64;

    if (tid < 64) {
        xsq_s[tid] = xsq[n0 + tid];
        red[tid] = ~0ull;
    }

    // ---- stage X tile (32 KB) into swizzled LDS, once --------------------
    const _Float16* xbase = xhl + (size_t)n0 * 256;
    #pragma unroll
    for (int i = 0; i < 8; ++i) {
        int idx = i * 256 + tid;              // 16B chunk index, 0..2047
        int r  = idx >> 5;                    // row 0..63
        int bc = (idx & 31) << 4;             // byte col 0..496
        f16x8 v = *(const f16x8*)(xbase + idx * 8);
        *(f16x8*)(xs + r * 512 + (bc ^ ((r & 7) << 4))) = v;
    }

    // head cols 0,1 of each enc row (bulk fill is +2-shifted for alignment)
    float* ebase = enc + (size_t)n0 * K_CODES;
    if (tid < 64) {
        float2 z2; z2.x = 0.f; z2.y = 0.f;
        *(float2*)(ebase + (size_t)tid * K_CODES) = z2;
    }
    __syncthreads();   // the ONLY barrier before the final reduce

    const int swz = (lq & 7) << 4;
    int rowb[4];
    #pragma unroll
    for (int i = 0; i < 4; ++i) rowb[i] = (i * 16 + lq) * 512;

    // per-lane W pointer: row (wk0 + lq), col quad*8
    const _Float16* wrow = whl + (size_t)(wk0 + lq) * 256 + quad * 8;
    // enc bulk fill: thread covers row tid>>2, float4 slots (tid&3)*8 + j
    float* efill = ebase + (size_t)(tid >> 2) * K_CODES + 2 + (tid & 3) * 32;
    const bool tail = ((tid & 3) == 3);

    f32x4 acc[4][2];
    unsigned long long pbest[4][4];
    #pragma unroll
    for (int i = 0; i < 4; ++i)
        #pragma unroll
        for (int j = 0; j < 4; ++j)
            pbest[i][j] = ~0ull;

    f16x8 bhA[2], blA[2], bhB[2], blB[2];
    #pragma unroll
    for (int ki = 0; ki < 2; ++ki) {          // W (kc=0,c0=0) -> set A
        bhA[ki] = *(const f16x8*)(wrow + ki * 4096);
        blA[ki] = *(const f16x8*)(wrow + ki * 4096 + 128);
    }

// one c0 step: X frags from LDS, prefetch next W from L2, 24 MFMAs.
#define STEP(c0_, CH, CL, PRE, PH, PL, preoff_)                               \
    do {                                                                       \
        f16x8 ah[4], al[4];                                                    \
        const int cb = (c0_) * 64 + quad * 16;                                 \
        _Pragma("unroll")                                                      \
        for (int i = 0; i < 4; ++i) {                                          \
            ah[i] = *(const f16x8*)(xs + rowb[i] + (cb ^ swz));                \
            al[i] = *(const f16x8*)(xs + rowb[i] + 256 + (cb ^ swz));          \
        }                                                                      \
        if (PRE) {                                                             \
            _Pragma("unroll")                                                  \
            for (int ki = 0; ki < 2; ++ki) {                                   \
                PH[ki] = *(const f16x8*)(wrow + (preoff_) + ki * 4096);        \
                PL[ki] = *(const f16x8*)(wrow + (preoff_) + ki * 4096 + 128);  \
            }                                                                  \
        }                                                                      \
        _Pragma("unroll")                                                      \
        for (int ki = 0; ki < 2; ++ki)                                         \
            _Pragma("unroll")                                                  \
            for (int ni = 0; ni < 4; ++ni) {                                   \
                acc[ni][ki] = __builtin_amdgcn_mfma_f32_16x16x32_f16(          \
                    ah[ni], CH[ki], acc[ni][ki], 0, 0, 0);                     \
                acc[ni][ki] = __builtin_amdgcn_mfma_f32_16x16x32_f16(          \
                    ah[ni], CL[ki], acc[ni][ki], 0, 0, 0);                     \
                acc[ni][ki] = __builtin_amdgcn_mfma_f32_16x16x32_f16(          \
                    al[ni], CH[ki], acc[ni][ki], 0, 0, 0);                     \
            }                                                                  \
    } while (0)

    for (int kc = 0; kc < 32; ++kc) {
        const int k0  = kc * 128;
        const int wko = kc * 32768;           // f16 offset of chunk in W

        const float wkv0 = wsq[k0 + wk0 + lq];
        const float wkv1 = wsq[k0 + wk0 + 16 + lq];

        // enc zero-fill for this chunk (drains lazily; no barriers)
        {
            float4 z4; z4.x = z4.y = z4.z = z4.w = 0.f;
            float* ef = efill + k0;
            #pragma unroll
            for (int j = 0; j < 8; ++j) {
                if (j == 7 && tail && kc == 31) {
                    float2 z2; z2.x = 0.f; z2.y = 0.f;
                    *(float2*)(ef + 28) = z2;     // cols 4094,4095: no spill
                } else {
                    *(float4*)(ef + j * 4) = z4;
                }
            }
        }

        #pragma unroll
        for (int i = 0; i < 4; ++i)
            #pragma unroll
            for (int j = 0; j < 2; ++j)
                acc[i][j] = (f32x4){0.f, 0.f, 0.f, 0.f};

        STEP(0, bhA, blA, 1, bhB, blB, wko + 32);
        STEP(1, bhB, blB, 1, bhA, blA, wko + 64);
        STEP(2, bhA, blA, 1, bhB, blB, wko + 96);
        if (kc < 31) STEP(3, bhB, blB, 1, bhA, blA, wko + 32768);
        else         STEP(3, bhB, blB, 0, bhA, blA, 0);

        // ---- per-chunk per-lane argmin update ----------------------------
        #pragma unroll
        for (int ni = 0; ni < 4; ++ni) {
            #pragma unroll
            for (int rg = 0; rg < 4; ++rg) {
                const int rowl = ni * 16 + quad * 4 + rg;
                const float xr = xsq_s[rowl];
                float best = 3.4e38f; int bk = 0;
                #pragma unroll
                for (int ki = 0; ki < 2; ++ki) {
                    int kl = wk0 + ki * 16 + lq;
                    float t = xr - acc[ni][ki][rg] * 6.103515625e-05f; // 2^-14
                    t += (ki ? wkv1 : wkv0);
                    t += 1e-8f;
                    if (t < best) { best = t; bk = k0 + kl; }
                }
                unsigned u = __float_as_uint(best);
                u = (u & 0x80000000u) ? ~u : (u | 0x80000000u);
                unsigned long long p =
                    ((unsigned long long)u << 32) | (unsigned)bk;
                if (p < pbest[ni][rg]) pbest[ni][rg] = p;   // strict: first-min
            }
        }
    }
#undef STEP

    // ---- block-local reduce: 16-lane shuffle + LDS u64 atomicMin ---------
    #pragma unroll
    for (int ni = 0; ni < 4; ++ni) {
        #pragma unroll
        for (int rg = 0; rg < 4; ++rg) {
            unsigned long long p = pbest[ni][rg];
            #pragma unroll
            for (int m = 1; m < 16; m <<= 1) {
                unsigned long long o = __shfl_xor(p, m, 64);
                if (o < p) p = o;
            }
            if (lq == 0) atomicMin(&red[ni * 16 + quad * 4 + rg], p);
        }
    }
    __syncthreads();   // also drains all enc zero stores (vmcnt(0))

    // ---- fused combine: idxf, one-hot 1.0, counts ------------------------
    if (tid < 64) {
        unsigned k = (unsigned)(red[tid] & 0xFFFFFFFFu);
        int n = n0 + tid;
        idxf[n] = (float)k;
        enc[(size_t)n * K_CODES + k] = 1.0f;
        atomicAdd(&counts[k], 1.0f);
    }
}

// ---------------- K6: gather -> quantized_st (NCHW) + per-block loss partial
__global__ __launch_bounds__(256) void quantize_loss(
    const float* __restrict__ x, const float* __restrict__ w,
    const float* __restrict__ idxf, float* __restrict__ outq,
    float* __restrict__ part)
{
    const int base4 = (blockIdx.x * 256 + threadIdx.x) * 4;
    float s = 0.f;
    #pragma unroll
    for (int i = 0; i < 4; ++i) {
        int e  = base4 + i * 1048576;      // NCHW element index (x4 aligned)
        int hw = e & 1023;
        int c  = (e >> 10) & 127;
        int b  = e >> 17;
        int n  = (b << 10) | hw;           // multiple of 4
        float4 xv = *(const float4*)(x + e);
        float4 kf = *(const float4*)(idxf + n);
        float q0 = w[(int)kf.x * DIM + c];
        float q1 = w[(int)kf.y * DIM + c];
        float q2 = w[(int)kf.z * DIM + c];
        float q3 = w[(int)kf.w * DIM + c];
        float4 df; df.x = q0 - xv.x; df.y = q1 - xv.y;
                   df.z = q2 - xv.z; df.w = q3 - xv.w;
        float4 o;  o.x = xv.x + df.x; o.y = xv.y + df.y;
                   o.z = xv.z + df.z; o.w = xv.w + df.w;
        *(float4*)(outq + e) = o;
        s = fmaf(df.x, df.x, s);
        s = fmaf(df.y, df.y, s);
        s = fmaf(df.z, df.z, s);
        s = fmaf(df.w, df.w, s);
    }
    #pragma unroll
    for (int o = 32; o > 0; o >>= 1) s += __shfl_down(s, o, 64);
    __shared__ float ls[4];
    if ((threadIdx.x & 63) == 0) ls[threadIdx.x >> 6] = s;
    __syncthreads();
    if (threadIdx.x == 0) part[blockIdx.x] = ls[0] + ls[1] + ls[2] + ls[3];
}

// ---------------- K7: loss (from partials) + perplexity ---------------------
__global__ __launch_bounds__(256) void finalize(
    const float* __restrict__ counts, const float* __restrict__ part,
    float* __restrict__ out)
{
    __shared__ float sh[512];
    float h = 0.f;
    for (int k = threadIdx.x; k < K_CODES; k += 256) {
        float p = counts[k] * (1.0f / N_FLAT);
        h += p * logf(p + 1e-10f);
    }
    float s = 0.f;
    for (int i = threadIdx.x; i < 1024; i += 256) s += part[i];
    sh[threadIdx.x] = h;
    sh[256 + threadIdx.x] = s;
    __syncthreads();
    #pragma unroll
    for (int st = 128; st > 0; st >>= 1) {
        if (threadIdx.x < st) {
            sh[threadIdx.x] += sh[threadIdx.x + st];
            sh[256 + threadIdx.x] += sh[256 + threadIdx.x + st];
        }
        __syncthreads();
    }
    if (threadIdx.x == 0) {
        float perp = expf(-sh[0]);
        float loss = 1.25f * (sh[256] / 4194304.0f);
        if (isnan(loss) || isinf(loss)) loss = 0.1f;
        out[OFF_LOSS] = loss;
        out[OFF_PERP] = perp;
    }
}

extern "C" void kernel_launch(void* const* d_in, const int* in_sizes, int n_in,
                              void* d_out, int out_size, void* d_ws, size_t ws_size,
                              hipStream_t stream) {
    const float* x = (const float*)d_in[0];   // [32,128,32,32] fp32 NCHW
    const float* w = (const float*)d_in[1];   // [4096,128] fp32
    float* out = (float*)d_out;
    char* ws = (char*)d_ws;

    float* counts = (float*)(ws + WS_COUNTS);
    float* wsq    = (float*)(ws + WS_WSQ);
    float* xsq    = (float*)(ws + WS_XSQ);
    float* part   = (float*)(ws + WS_PART);
    _Float16* xhl = (_Float16*)(ws + WS_XHL);
    _Float16* whl = (_Float16*)(ws + WS_WHL);

    wsq_kernel<<<K_CODES / 4, 256, 0, stream>>>(w, wsq, counts);
    wplanes_kernel<<<K_CODES * 4 / 256, 256, 0, stream>>>(w, whl);
    xprep_kernel<<<N_FLAT / 64, 256, 0, stream>>>(x, xhl, xsq);

    dist_argmin<<<N_FLAT / 64, 256, 0, stream>>>(xhl, whl, wsq, xsq,
                                                 out + OFF_IDX,
                                                 out + OFF_ENC, counts);

    quantize_loss<<<1024, 256, 0, stream>>>(x, w, out + OFF_IDX,
                                            out + OFF_Q, part);

    finalize<<<1, 256, 0, stream>>>(counts, part, out);
}

// Round 7
// 869.183 us; speedup vs baseline: 1.0815x; 1.0263x over previous
//
#include <hip/hip_runtime.h>
#include <stdint.h>
#include <math.h>

#define K_CODES 4096
#define DIM 128
#define N_FLAT 32768      // 32 * 32 * 32
#define HW 1024           // 32*32 spatial per batch

// output offsets (floats): quantized_st, loss, perplexity, encodings, indices
#define OFF_Q    0
#define OFF_LOSS 4194304
#define OFF_PERP 4194305
#define OFF_ENC  4194306
#define OFF_IDX  138412034

// workspace offsets (bytes)
#define WS_COUNTS 262144                   // 4096 * 4
#define WS_WSQ    278528                   // 4096 * 4
#define WS_XSQ    294912                   // 32768 * 4
#define WS_PART   425984                   // 1024 * 4
#define WS_XHL    430080                   // 32768 rows * 256 f16 = 16 MB
#define WS_WHL    (WS_XHL + 16777216)      // 4096 rows * 256 f16 = 2 MB

typedef _Float16 f16x8 __attribute__((ext_vector_type(8)));
typedef float    f32x4 __attribute__((ext_vector_type(4)));

// f16 plane rows: [row][0:128]=h, [row][128:256]=l (512 B). Exact pow2
// scales x*32, w*1024 -> acc = 2^15*dot, unscale by 2^-14 is exact.

// ---------------- K1: w_sq + counts zero. grid 1024 x 256 (4 waves = 4 k) --
__global__ __launch_bounds__(256) void wsq_kernel(const float* __restrict__ w,
                                                  float* __restrict__ wsq,
                                                  float* __restrict__ counts) {
    int wave = threadIdx.x >> 6, lane = threadIdx.x & 63;
    int k = blockIdx.x * 4 + wave;
    float a = w[k * DIM + lane];
    float b = w[k * DIM + lane + 64];
    float s = a * a + b * b;
    #pragma unroll
    for (int o = 32; o > 0; o >>= 1) s += __shfl_down(s, o, 64);
    if (lane == 0) { wsq[k] = s; counts[k] = 0.f; }
}

// ---------------- K2: w -> f16 h/l planes ----------------------------------
__global__ __launch_bounds__(256) void wplanes_kernel(const float* __restrict__ w,
                                                      _Float16* __restrict__ whl) {
    int T = blockIdx.x * 256 + threadIdx.x;
    int k = T >> 2, seg = T & 3;
    const float* wp = w + (size_t)k * DIM + seg * 32;
    _Float16* row = whl + (size_t)k * 256;
    #pragma unroll
    for (int q = 0; q < 4; ++q) {
        float4 a = *(const float4*)(wp + q * 8);
        float4 b = *(const float4*)(wp + q * 8 + 4);
        float vv[8] = {a.x, a.y, a.z, a.w, b.x, b.y, b.z, b.w};
        f16x8 hv, lv;
        #pragma unroll
        for (int j = 0; j < 8; ++j) {
            float v = 1024.0f * vv[j];
            _Float16 h = (_Float16)v;
            _Float16 l = (_Float16)(v - (float)h);
            hv[j] = h; lv[j] = l;
        }
        *(f16x8*)(row + seg * 32 + q * 8) = hv;
        *(f16x8*)(row + 128 + seg * 32 + q * 8) = lv;
    }
}

// ---------------- K3: x -> planes + x_sq (fused) ---------------------------
__global__ __launch_bounds__(256) void xprep_kernel(const float* __restrict__ x,
                                                    _Float16* __restrict__ xhl,
                                                    float* __restrict__ xsq) {
    __shared__ float xt[128 * 65];            // [c][n], pad 65
    const int t = threadIdx.x;
    const int n0 = blockIdx.x * 64;
    const int b = n0 >> 10, hw0 = n0 & 1023;
    const float* xg = x + (size_t)b * (DIM * HW) + hw0;
    #pragma unroll
    for (int i = 0; i < 16; ++i) {
        int idx = i * 256 + t;                // 4096 float2
        int c = idx >> 5, n2 = (idx & 31) << 1;
        float2 v = *(const float2*)(xg + c * HW + n2);
        xt[c * 65 + n2] = v.x;
        xt[c * 65 + n2 + 1] = v.y;
    }
    __syncthreads();
    if (t < 64) {
        float s = 0.f;                        // strict c order, fp32 (== ref path)
        #pragma unroll
        for (int c = 0; c < DIM; ++c) {
            float v = xt[c * 65 + t];
            s = fmaf(v, v, s);
        }
        xsq[n0 + t] = s;
    }
    const int n = t >> 2, seg = t & 3;
    _Float16* row = xhl + (size_t)(n0 + n) * 256;
    #pragma unroll
    for (int q = 0; q < 4; ++q) {
        f16x8 hv, lv;
        #pragma unroll
        for (int j = 0; j < 8; ++j) {
            float v = 32.0f * xt[(seg * 32 + q * 8 + j) * 65 + n];
            _Float16 h = (_Float16)v;
            _Float16 l = (_Float16)(v - (float)h);
            hv[j] = h; lv[j] = l;
        }
        *(f16x8*)(row + seg * 32 + q * 8) = hv;
        *(f16x8*)(row + 128 + seg * 32 + q * 8) = lv;
    }
}

// ---------------- K4 (R7): full-K per block, 32 rows, fused argmin+combine -
// grid 1024 blocks x 256 thr (4 waves). Block owns 32 n-rows x ALL 4096 k
// (32 chunks of 128). Wave w covers k-col [w*32, w*32+32), ALL 32 rows:
// acc[2][2] (16 VGPR), W dbuf 32, pbest[2][4] 16 -> ~120 live, no forced
// launch bound (R2/R5 lesson), 3-4 waves/SIMD.
// R7 vs R6 (post-mortem: occupancy 11.9%, scattered enc stores @1.56TB/s):
//  - 2x blocks (1024): restores latency hiding.
//  - enc zero-fill COALESCED (R3 mapping: consecutive lanes -> consecutive
//    float4 in a row); tail threads (tid&31==31) write float2 at kc=31 so
//    no write leaves the block's rows. Head cols 0,1 per row via z2.
//  - everything else structurally identical to R6 (X once in swizzled LDS,
//    one barrier; W per-lane from L2 with A/B prefetch; block-local argmin;
//    fused combine). Numerics bit-identical per (n,k).
__global__ __launch_bounds__(256) void dist_argmin(
    const _Float16* __restrict__ xhl, const _Float16* __restrict__ whl,
    const float* __restrict__ wsq, const float* __restrict__ xsq,
    float* __restrict__ idxf, float* __restrict__ enc,
    float* __restrict__ counts)
{
    __shared__ __align__(16) char xs[32 * 512];      // X tile, swizzled, 16 KB
    __shared__ float xsq_s[32];
    __shared__ unsigned long long red[32];

    const int tid  = threadIdx.x;
    const int lane = tid & 63, wave = tid >> 6;
    const int lq   = lane & 15, quad = lane >> 4;
    const int wk0  = wave * 32;              // k offset within 128-chunk
    const int n0   = blockIdx.x * 32;

    if (tid < 32) {
        xsq_s[tid] = xsq[n0 + tid];
        red[tid] = ~0ull;
    }

    // ---- stage X tile (16 KB) into swizzled LDS, once --------------------
    const _Float16* xbase = xhl + (size_t)n0 * 256;
    #pragma unroll
    for (int i = 0; i < 4; ++i) {
        int idx = i * 256 + tid;              // 16B chunk index, 0..1023
        int r  = idx >> 5;                    // row 0..31
        int bc = (idx & 31) << 4;             // byte col 0..496
        f16x8 v = *(const f16x8*)(xbase + idx * 8);
        *(f16x8*)(xs + r * 512 + (bc ^ ((r & 7) << 4))) = v;
    }

    // head cols 0,1 of each enc row (bulk fill is +2-shifted for alignment)
    float* ebase = enc + (size_t)n0 * K_CODES;
    if (tid < 32) {
        float2 z2; z2.x = 0.f; z2.y = 0.f;
        *(float2*)(ebase + (size_t)tid * K_CODES) = z2;
    }
    __syncthreads();   // the ONLY barrier before the final reduce

    const int swz = (lq & 7) << 4;
    int rowb[2];
    #pragma unroll
    for (int i = 0; i < 2; ++i) rowb[i] = (i * 16 + lq) * 512;

    // per-lane W pointer: row (wk0 + lq), col quad*8
    const _Float16* wrow = whl + (size_t)(wk0 + lq) * 256 + quad * 8;
    const bool tail = ((tid & 31) == 31);

    f32x4 acc[2][2];
    unsigned long long pbest[2][4];
    #pragma unroll
    for (int i = 0; i < 2; ++i)
        #pragma unroll
        for (int j = 0; j < 4; ++j)
            pbest[i][j] = ~0ull;

    f16x8 bhA[2], blA[2], bhB[2], blB[2];
    #pragma unroll
    for (int ki = 0; ki < 2; ++ki) {          // W (kc=0,c0=0) -> set A
        bhA[ki] = *(const f16x8*)(wrow + ki * 4096);
        blA[ki] = *(const f16x8*)(wrow + ki * 4096 + 128);
    }

// one c0 step: X frags from LDS, prefetch next W from L2, 12 MFMAs.
#define STEP(c0_, CH, CL, PRE, PH, PL, preoff_)                               \
    do {                                                                       \
        f16x8 ah[2], al[2];                                                    \
        const int cb = (c0_) * 64 + quad * 16;                                 \
        _Pragma("unroll")                                                      \
        for (int i = 0; i < 2; ++i) {                                          \
            ah[i] = *(const f16x8*)(xs + rowb[i] + (cb ^ swz));                \
            al[i] = *(const f16x8*)(xs + rowb[i] + 256 + (cb ^ swz));          \
        }                                                                      \
        if (PRE) {                                                             \
            _Pragma("unroll")                                                  \
            for (int ki = 0; ki < 2; ++ki) {                                   \
                PH[ki] = *(const f16x8*)(wrow + (preoff_) + ki * 4096);        \
                PL[ki] = *(const f16x8*)(wrow + (preoff_) + ki * 4096 + 128);  \
            }                                                                  \
        }                                                                      \
        _Pragma("unroll")                                                      \
        for (int ki = 0; ki < 2; ++ki)                                         \
            _Pragma("unroll")                                                  \
            for (int ni = 0; ni < 2; ++ni) {                                   \
                acc[ni][ki] = __builtin_amdgcn_mfma_f32_16x16x32_f16(          \
                    ah[ni], CH[ki], acc[ni][ki], 0, 0, 0);                     \
                acc[ni][ki] = __builtin_amdgcn_mfma_f32_16x16x32_f16(          \
                    ah[ni], CL[ki], acc[ni][ki], 0, 0, 0);                     \
                acc[ni][ki] = __builtin_amdgcn_mfma_f32_16x16x32_f16(          \
                    al[ni], CH[ki], acc[ni][ki], 0, 0, 0);                     \
            }                                                                  \
    } while (0)

    for (int kc = 0; kc < 32; ++kc) {
        const int k0  = kc * 128;
        const int wko = kc * 32768;           // f16 offset of chunk in W

        const float wkv0 = wsq[k0 + wk0 + lq];
        const float wkv1 = wsq[k0 + wk0 + 16 + lq];

        // enc zero-fill for this chunk: COALESCED. 32 rows x 128 cols =
        // 1024 float4; thread covers idx = j*256+tid -> row idx>>5, slot
        // idx&31 (== tid&31, row-contiguous across lanes). +2 shift; the
        // c4==31 float4 at kc==31 would hit cols 4094..4097 -> float2.
        {
            float4 z4; z4.x = z4.y = z4.z = z4.w = 0.f;
            #pragma unroll
            for (int j = 0; j < 4; ++j) {
                int idx = j * 256 + tid;
                float* ef = ebase + (size_t)(idx >> 5) * K_CODES + k0 + 2
                          + (idx & 31) * 4;
                if (tail && kc == 31) {
                    float2 z2; z2.x = 0.f; z2.y = 0.f;
                    *(float2*)ef = z2;            // cols 4094,4095 only
                } else {
                    *(float4*)ef = z4;
                }
            }
        }

        #pragma unroll
        for (int i = 0; i < 2; ++i)
            #pragma unroll
            for (int j = 0; j < 2; ++j)
                acc[i][j] = (f32x4){0.f, 0.f, 0.f, 0.f};

        STEP(0, bhA, blA, 1, bhB, blB, wko + 32);
        STEP(1, bhB, blB, 1, bhA, blA, wko + 64);
        STEP(2, bhA, blA, 1, bhB, blB, wko + 96);
        if (kc < 31) STEP(3, bhB, blB, 1, bhA, blA, wko + 32768);
        else         STEP(3, bhB, blB, 0, bhA, blA, 0);

        // ---- per-chunk per-lane argmin update ----------------------------
        #pragma unroll
        for (int ni = 0; ni < 2; ++ni) {
            #pragma unroll
            for (int rg = 0; rg < 4; ++rg) {
                const int rowl = ni * 16 + quad * 4 + rg;
                const float xr = xsq_s[rowl];
                float best = 3.4e38f; int bk = 0;
                #pragma unroll
                for (int ki = 0; ki < 2; ++ki) {
                    int kl = wk0 + ki * 16 + lq;
                    float t = xr - acc[ni][ki][rg] * 6.103515625e-05f; // 2^-14
                    t += (ki ? wkv1 : wkv0);
                    t += 1e-8f;
                    if (t < best) { best = t; bk = k0 + kl; }
                }
                unsigned u = __float_as_uint(best);
                u = (u & 0x80000000u) ? ~u : (u | 0x80000000u);
                unsigned long long p =
                    ((unsigned long long)u << 32) | (unsigned)bk;
                if (p < pbest[ni][rg]) pbest[ni][rg] = p;   // strict: first-min
            }
        }
    }
#undef STEP

    // ---- block-local reduce: 16-lane shuffle + LDS u64 atomicMin ---------
    #pragma unroll
    for (int ni = 0; ni < 2; ++ni) {
        #pragma unroll
        for (int rg = 0; rg < 4; ++rg) {
            unsigned long long p = pbest[ni][rg];
            #pragma unroll
            for (int m = 1; m < 16; m <<= 1) {
                unsigned long long o = __shfl_xor(p, m, 64);
                if (o < p) p = o;
            }
            if (lq == 0) atomicMin(&red[ni * 16 + quad * 4 + rg], p);
        }
    }
    __syncthreads();   // also drains all enc zero stores (vmcnt(0))

    // ---- fused combine: idxf, one-hot 1.0, counts ------------------------
    if (tid < 32) {
        unsigned k = (unsigned)(red[tid] & 0xFFFFFFFFu);
        int n = n0 + tid;
        idxf[n] = (float)k;
        enc[(size_t)n * K_CODES + k] = 1.0f;
        atomicAdd(&counts[k], 1.0f);
    }
}

// ---------------- K6: gather -> quantized_st (NCHW) + per-block loss partial
__global__ __launch_bounds__(256) void quantize_loss(
    const float* __restrict__ x, const float* __restrict__ w,
    const float* __restrict__ idxf, float* __restrict__ outq,
    float* __restrict__ part)
{
    const int base4 = (blockIdx.x * 256 + threadIdx.x) * 4;
    float s = 0.f;
    #pragma unroll
    for (int i = 0; i < 4; ++i) {
        int e  = base4 + i * 1048576;      // NCHW element index (x4 aligned)
        int hw = e & 1023;
        int c  = (e >> 10) & 127;
        int b  = e >> 17;
        int n  = (b << 10) | hw;           // multiple of 4
        float4 xv = *(const float4*)(x + e);
        float4 kf = *(const float4*)(idxf + n);
        float q0 = w[(int)kf.x * DIM + c];
        float q1 = w[(int)kf.y * DIM + c];
        float q2 = w[(int)kf.z * DIM + c];
        float q3 = w[(int)kf.w * DIM + c];
        float4 df; df.x = q0 - xv.x; df.y = q1 - xv.y;
                   df.z = q2 - xv.z; df.w = q3 - xv.w;
        float4 o;  o.x = xv.x + df.x; o.y = xv.y + df.y;
                   o.z = xv.z + df.z; o.w = xv.w + df.w;
        *(float4*)(outq + e) = o;
        s = fmaf(df.x, df.x, s);
        s = fmaf(df.y, df.y, s);
        s = fmaf(df.z, df.z, s);
        s = fmaf(df.w, df.w, s);
    }
    #pragma unroll
    for (int o = 32; o > 0; o >>= 1) s += __shfl_down(s, o, 64);
    __shared__ float ls[4];
    if ((threadIdx.x & 63) == 0) ls[threadIdx.x >> 6] = s;
    __syncthreads();
    if (threadIdx.x == 0) part[blockIdx.x] = ls[0] + ls[1] + ls[2] + ls[3];
}

// ---------------- K7: loss (from partials) + perplexity ---------------------
__global__ __launch_bounds__(256) void finalize(
    const float* __restrict__ counts, const float* __restrict__ part,
    float* __restrict__ out)
{
    __shared__ float sh[512];
    float h = 0.f;
    for (int k = threadIdx.x; k < K_CODES; k += 256) {
        float p = counts[k] * (1.0f / N_FLAT);
        h += p * logf(p + 1e-10f);
    }
    float s = 0.f;
    for (int i = threadIdx.x; i < 1024; i += 256) s += part[i];
    sh[threadIdx.x] = h;
    sh[256 + threadIdx.x] = s;
    __syncthreads();
    #pragma unroll
    for (int st = 128; st > 0; st >>= 1) {
        if (threadIdx.x < st) {
            sh[threadIdx.x] += sh[threadIdx.x + st];
            sh[256 + threadIdx.x] += sh[256 + threadIdx.x + st];
        }
        __syncthreads();
    }
    if (threadIdx.x == 0) {
        float perp = expf(-sh[0]);
        float loss = 1.25f * (sh[256] / 4194304.0f);
        if (isnan(loss) || isinf(loss)) loss = 0.1f;
        out[OFF_LOSS] = loss;
        out[OFF_PERP] = perp;
    }
}

extern "C" void kernel_launch(void* const* d_in, const int* in_sizes, int n_in,
                              void* d_out, int out_size, void* d_ws, size_t ws_size,
                              hipStream_t stream) {
    const float* x = (const float*)d_in[0];   // [32,128,32,32] fp32 NCHW
    const float* w = (const float*)d_in[1];   // [4096,128] fp32
    float* out = (float*)d_out;
    char* ws = (char*)d_ws;

    float* counts = (float*)(ws + WS_COUNTS);
    float* wsq    = (float*)(ws + WS_WSQ);
    float* xsq    = (float*)(ws + WS_XSQ);
    float* part   = (float*)(ws + WS_PART);
    _Float16* xhl = (_Float16*)(ws + WS_XHL);
    _Float16* whl = (_Float16*)(ws + WS_WHL);

    wsq_kernel<<<K_CODES / 4, 256, 0, stream>>>(w, wsq, counts);
    wplanes_kernel<<<K_CODES * 4 / 256, 256, 0, stream>>>(w, whl);
    xprep_kernel<<<N_FLAT / 64, 256, 0, stream>>>(x, xhl, xsq);

    dist_argmin<<<N_FLAT / 32, 256, 0, stream>>>(xhl, whl, wsq, xsq,
                                                 out + OFF_IDX,
                                                 out + OFF_ENC, counts);

    quantize_loss<<<1024, 256, 0, stream>>>(x, w, out + OFF_IDX,
                                            out + OFF_Q, part);

    finalize<<<1, 256, 0, stream>>>(counts, part, out);
}

// Round 9
// 770.104 us; speedup vs baseline: 1.2206x; 1.1287x over previous
//
#include <hip/hip_runtime.h>
#include <stdint.h>
#include <math.h>

#define K_CODES 4096
#define DIM 128
#define N_FLAT 32768      // 32 * 32 * 32
#define HW 1024           // 32*32 spatial per batch

// output offsets (floats): quantized_st, loss, perplexity, encodings, indices
#define OFF_Q    0
#define OFF_LOSS 4194304
#define OFF_PERP 4194305
#define OFF_ENC  4194306
#define OFF_IDX  138412034

// workspace offsets (bytes)
#define WS_PACKED 0                        // 32768 * 8
#define WS_COUNTS 262144                   // 4096 * 4
#define WS_WSQ    278528                   // 4096 * 4
#define WS_XSQ    294912                   // 32768 * 4
#define WS_PART   425984                   // 1024 * 4
#define WS_XHL    430080                   // 32768 rows * 256 f16 = 16 MB
#define WS_WHL    (WS_XHL + 16777216)      // 4096 rows * 256 f16 = 2 MB

typedef _Float16 f16x8 __attribute__((ext_vector_type(8)));
typedef float    f32x4 __attribute__((ext_vector_type(4)));

// f16 plane rows: [row][0:128]=h, [row][128:256]=l (512 B). Exact pow2
// scales x*32, w*1024 -> acc = 2^15*dot, unscale by 2^-14 is exact.

// ---------------- K1: w_sq + counts zero. grid 1024 x 256 (4 waves = 4 k) --
__global__ __launch_bounds__(256) void wsq_kernel(const float* __restrict__ w,
                                                  float* __restrict__ wsq,
                                                  float* __restrict__ counts) {
    int wave = threadIdx.x >> 6, lane = threadIdx.x & 63;
    int k = blockIdx.x * 4 + wave;
    float a = w[k * DIM + lane];
    float b = w[k * DIM + lane + 64];
    float s = a * a + b * b;
    #pragma unroll
    for (int o = 32; o > 0; o >>= 1) s += __shfl_down(s, o, 64);
    if (lane == 0) { wsq[k] = s; counts[k] = 0.f; }
}

// ---------------- K2: w -> f16 h/l planes ----------------------------------
__global__ __launch_bounds__(256) void wplanes_kernel(const float* __restrict__ w,
                                                      _Float16* __restrict__ whl) {
    int T = blockIdx.x * 256 + threadIdx.x;
    int k = T >> 2, seg = T & 3;
    const float* wp = w + (size_t)k * DIM + seg * 32;
    _Float16* row = whl + (size_t)k * 256;
    #pragma unroll
    for (int q = 0; q < 4; ++q) {
        float4 a = *(const float4*)(wp + q * 8);
        float4 b = *(const float4*)(wp + q * 8 + 4);
        float vv[8] = {a.x, a.y, a.z, a.w, b.x, b.y, b.z, b.w};
        f16x8 hv, lv;
        #pragma unroll
        for (int j = 0; j < 8; ++j) {
            float v = 1024.0f * vv[j];
            _Float16 h = (_Float16)v;
            _Float16 l = (_Float16)(v - (float)h);
            hv[j] = h; lv[j] = l;
        }
        *(f16x8*)(row + seg * 32 + q * 8) = hv;
        *(f16x8*)(row + 128 + seg * 32 + q * 8) = lv;
    }
}

// ---------------- K3: x -> planes + x_sq + packed init (fused) -------------
__global__ __launch_bounds__(256) void xprep_kernel(const float* __restrict__ x,
                                                    _Float16* __restrict__ xhl,
                                                    float* __restrict__ xsq,
                                                    unsigned long long* __restrict__ packed) {
    __shared__ float xt[128 * 65];            // [c][n], pad 65
    const int t = threadIdx.x;
    const int n0 = blockIdx.x * 64;
    const int b = n0 >> 10, hw0 = n0 & 1023;
    const float* xg = x + (size_t)b * (DIM * HW) + hw0;
    #pragma unroll
    for (int i = 0; i < 16; ++i) {
        int idx = i * 256 + t;                // 4096 float2
        int c = idx >> 5, n2 = (idx & 31) << 1;
        float2 v = *(const float2*)(xg + c * HW + n2);
        xt[c * 65 + n2] = v.x;
        xt[c * 65 + n2 + 1] = v.y;
    }
    __syncthreads();
    if (t < 64) {
        packed[n0 + t] = ~0ull;
        float s = 0.f;                        // strict c order, fp32 (== ref path)
        #pragma unroll
        for (int c = 0; c < DIM; ++c) {
            float v = xt[c * 65 + t];
            s = fmaf(v, v, s);
        }
        xsq[n0 + t] = s;
    }
    const int n = t >> 2, seg = t & 3;
    _Float16* row = xhl + (size_t)(n0 + n) * 256;
    #pragma unroll
    for (int q = 0; q < 4; ++q) {
        f16x8 hv, lv;
        #pragma unroll
        for (int j = 0; j < 8; ++j) {
            float v = 32.0f * xt[(seg * 32 + q * 8 + j) * 65 + n];
            _Float16 h = (_Float16)v;
            _Float16 l = (_Float16)(v - (float)h);
            hv[j] = h; lv[j] = l;
        }
        *(f16x8*)(row + seg * 32 + q * 8) = hv;
        *(f16x8*)(row + 128 + seg * 32 + q * 8) = lv;
    }
}

// ---------------- K4 (R8): split-K MFMA GEMM, global_load_lds staging ------
// grid (256 n-tiles, 8 k-supertiles), block 256 = 4 waves 2x2, 128n x 512k
// per block, 16 (ks,c0) steps, LDS double-buffered, ONE barrier per step.
// R8 = R4's verified structure (K4 ~210us, best measured) with:
//  (a) global_load_lds width=16 staging (no reg round-trip; guide C-mist #1).
//      LDS layout LINEAR [128 rows][128 B] per buffer. T21 both-sides
//      swizzle: physical col pc holds logical col lc = pc ^ ((row&7)<<4);
//      achieved by pre-swizzling the per-lane GLOBAL source address (the
//      LDS dest stays base+lane*16 linear, wave-uniform base = buf +
//      wave*4096 + i*1024). Reads use the same XOR. Verified by trace:
//      row1 read h-col0 -> phys16, whose writer lane fetched lc=0 (h f16
//      0..7). Read conflicts: 16 lanes -> 8 slots x 2 rows = 2-way (free).
//  (b) R3's in-kernel coalesced enc zero-fill (proven absmax 0; spill
//      floats 512/513 land on a neighbor's head-z2 = zero-over-zero;
//      last row's spill into idx region overwritten by combine after).
//  (c) R4's per-ks epilogue: per-lane argmin, 16-lane shuffle, LDS u64
//      atomicMin red[], ONE global atomicMin per row at the end.
//  Numerics bit-identical: same staged values, same MFMA order (hH,hL,lH,
//  c0 ascending), same t formula / packed-u64 tie-break.
__global__ __launch_bounds__(256) void dist_argmin(
    const _Float16* __restrict__ xhl, const _Float16* __restrict__ whl,
    const float* __restrict__ wsq, const float* __restrict__ xsq,
    unsigned long long* __restrict__ packed, float* __restrict__ enc)
{
    __shared__ __align__(16) char xlds[2][16384];   // [row][128B] linear
    __shared__ __align__(16) char wlds[2][16384];
    __shared__ float xsq_s[128];
    __shared__ unsigned long long red[128];

    const int tid  = threadIdx.x;
    const int lane = tid & 63, wave = tid >> 6;
    const int lq   = lane & 15, quad = lane >> 4;
    const int wn0  = (wave >> 1) * 64, wk0 = (wave & 1) * 64;
    const int n0   = blockIdx.x * 128;
    const int kbase = blockIdx.y * 512;

    // ---- staging constants (gload_lds dest = buf + wave*4096 + i*1024 +
    // lane*16 -> row = wave*32 + i*8 + (lane>>3), pc = (lane&7)*16) --------
    const int r0 = wave * 32 + (lane >> 3);               // row at i=0
    const int lc = (((lane & 7) ^ (lane >> 3)) << 4);     // logical byte col
    const int lcAdj = lc + ((lc >> 6) * 192);             // l-plane: +192
    const char* xB = (const char*)xhl;
    const char* wB = (const char*)whl;
    const size_t xrow0 = (size_t)(n0 + r0) * 512;

    // ---- fragment read offsets (logical [h32|l32] row, XOR swizzle) ------
    const int swz  = (lq & 7) << 4;
    const int hoff = (quad << 4) ^ swz;
    const int loff = (64 | (quad << 4)) ^ swz;

    float* ebase = enc + (size_t)n0 * K_CODES + kbase;
    if (tid < 128) {
        float2 z2; z2.x = 0.f; z2.y = 0.f;
        *(float2*)(ebase + (size_t)tid * K_CODES) = z2;   // head cols 0..1
        xsq_s[tid] = xsq[n0 + tid];
        red[tid] = ~0ull;
    }

#define GLOAD16(gp, lp) __builtin_amdgcn_global_load_lds(                      \
        (const __attribute__((address_space(1))) void*)(gp),                   \
        (__attribute__((address_space(3))) void*)(lp), 16, 0, 0)

    // ---- prologue: stage step 0 (ks=0, c0=0) into buffer 0 ---------------
    {
        const size_t wrow0 = (size_t)(kbase + r0) * 512;
        #pragma unroll
        for (int i = 0; i < 4; ++i) {
            GLOAD16(xB + xrow0 + (size_t)i * 4096 + lcAdj,
                    xlds[0] + wave * 4096 + i * 1024);
            GLOAD16(wB + wrow0 + (size_t)i * 4096 + lcAdj,
                    wlds[0] + wave * 4096 + i * 1024);
        }
    }

    f32x4 acc[4][4];
    float wk[4];

    for (int s = 0; s < 16; ++s) {
        const int p  = s & 1;
        const int ks = s >> 2, c0 = s & 3;
        const int k0 = kbase + ks * 128;
        if (c0 == 0) {
            #pragma unroll
            for (int ki = 0; ki < 4; ++ki)
                wk[ki] = wsq[k0 + wk0 + ki * 16 + lq];   // L1-hot, fp32-exact
            #pragma unroll
            for (int i = 0; i < 4; ++i)
                #pragma unroll
                for (int j = 0; j < 4; ++j)
                    acc[i][j] = (f32x4){0.f, 0.f, 0.f, 0.f};
        }
        // barrier: compiler drains vmcnt(0) first -> step-s staging landed;
        // also guarantees all waves' step s-1 LDS reads are done, so the
        // gload_lds issued below into buf[p^1] cannot clobber live data.
        __syncthreads();

        // frag reads from buf[p]
        f16x8 ah[4], al[4], bh[4], bl[4];
        const char* xb = xlds[p];
        const char* wb = wlds[p];
        #pragma unroll
        for (int i = 0; i < 4; ++i) {
            int xr = (wn0 + 16 * i + lq) * 128;
            ah[i] = *(const f16x8*)(xb + xr + hoff);
            al[i] = *(const f16x8*)(xb + xr + loff);
            int wr = (wk0 + 16 * i + lq) * 128;
            bh[i] = *(const f16x8*)(wb + wr + hoff);
            bl[i] = *(const f16x8*)(wb + wr + loff);
        }

        // stage step s+1 into buf[p^1] (async; completes by next barrier)
        if (s < 15) {
            const int s1 = s + 1, ks1 = s1 >> 2, c01 = s1 & 3;
            const int offX = c01 * 64 + lcAdj;
            const size_t wrow0 = (size_t)(kbase + ks1 * 128 + r0) * 512;
            char* xd = xlds[p ^ 1] + wave * 4096;
            char* wd = wlds[p ^ 1] + wave * 4096;
            #pragma unroll
            for (int i = 0; i < 4; ++i) {
                GLOAD16(xB + xrow0 + (size_t)i * 4096 + offX, xd + i * 1024);
                GLOAD16(wB + wrow0 + (size_t)i * 4096 + offX, wd + i * 1024);
            }
        }

        // enc zero-fill batch s (R3 mapping, coalesced)
        {
            float4 z4; z4.x = z4.y = z4.z = z4.w = 0.f;
            #pragma unroll
            for (int j = 0; j < 4; ++j) {
                int idx = s * 1024 + j * 256 + tid;
                int r = idx >> 7, c4 = idx & 127;
                *(float4*)(ebase + (size_t)r * K_CODES + 2 + c4 * 4) = z4;
            }
        }

        #pragma unroll
        for (int ki = 0; ki < 4; ++ki)
            #pragma unroll
            for (int ni = 0; ni < 4; ++ni) {
                acc[ni][ki] = __builtin_amdgcn_mfma_f32_16x16x32_f16(
                    ah[ni], bh[ki], acc[ni][ki], 0, 0, 0);
                acc[ni][ki] = __builtin_amdgcn_mfma_f32_16x16x32_f16(
                    ah[ni], bl[ki], acc[ni][ki], 0, 0, 0);
                acc[ni][ki] = __builtin_amdgcn_mfma_f32_16x16x32_f16(
                    al[ni], bh[ki], acc[ni][ki], 0, 0, 0);
            }

        if (c0 == 3) {   // per-ks epilogue: distances + argmin -> LDS red[]
            #pragma unroll
            for (int ni = 0; ni < 4; ++ni) {
                #pragma unroll
                for (int rg = 0; rg < 4; ++rg) {
                    int rowl = wn0 + ni * 16 + quad * 4 + rg;
                    float xr = xsq_s[rowl];
                    float best = 3.4e38f; int bk = 0;
                    #pragma unroll
                    for (int ki = 0; ki < 4; ++ki) {
                        int kl = wk0 + ki * 16 + lq;
                        float t = xr - acc[ni][ki][rg] * 6.103515625e-05f; // 2^-14
                        t += wk[ki];
                        t += 1e-8f;
                        if (t < best) { best = t; bk = k0 + kl; }
                    }
                    unsigned u = __float_as_uint(best);
                    u = (u & 0x80000000u) ? ~u : (u | 0x80000000u);
                    unsigned long long pck =
                        ((unsigned long long)u << 32) | (unsigned)bk;
                    #pragma unroll
                    for (int m = 1; m < 16; m <<= 1) {
                        unsigned long long o = __shfl_xor(pck, m, 64);
                        if (o < pck) pck = o;
                    }
                    if (lq == 0) atomicMin(&red[rowl], pck);
                }
            }
        }
    }
#undef GLOAD16

    __syncthreads();
    if (tid < 128) atomicMin(&packed[n0 + tid], red[tid]);
}

// ---------------- K5: combine -> indices, one-hot 1.0, counts ---------------
__global__ __launch_bounds__(256) void combine(
    const unsigned long long* __restrict__ packed,
    float* __restrict__ idxf, float* __restrict__ enc,
    float* __restrict__ counts)
{
    int n = blockIdx.x * 256 + threadIdx.x;
    unsigned k = (unsigned)(packed[n] & 0xFFFFFFFFu);
    idxf[n] = (float)k;
    enc[(size_t)n * K_CODES + k] = 1.0f;
    atomicAdd(&counts[k], 1.0f);
}

// ---------------- K6: gather -> quantized_st (NCHW) + per-block loss partial
__global__ __launch_bounds__(256) void quantize_loss(
    const float* __restrict__ x, const float* __restrict__ w,
    const float* __restrict__ idxf, float* __restrict__ outq,
    float* __restrict__ part)
{
    const int base4 = (blockIdx.x * 256 + threadIdx.x) * 4;
    float s = 0.f;
    #pragma unroll
    for (int i = 0; i < 4; ++i) {
        int e  = base4 + i * 1048576;      // NCHW element index (x4 aligned)
        int hw = e & 1023;
        int c  = (e >> 10) & 127;
        int b  = e >> 17;
        int n  = (b << 10) | hw;           // multiple of 4
        float4 xv = *(const float4*)(x + e);
        float4 kf = *(const float4*)(idxf + n);
        float q0 = w[(int)kf.x * DIM + c];
        float q1 = w[(int)kf.y * DIM + c];
        float q2 = w[(int)kf.z * DIM + c];
        float q3 = w[(int)kf.w * DIM + c];
        float4 df; df.x = q0 - xv.x; df.y = q1 - xv.y;
                   df.z = q2 - xv.z; df.w = q3 - xv.w;
        float4 o;  o.x = xv.x + df.x; o.y = xv.y + df.y;
                   o.z = xv.z + df.z; o.w = xv.w + df.w;
        *(float4*)(outq + e) = o;
        s = fmaf(df.x, df.x, s);
        s = fmaf(df.y, df.y, s);
        s = fmaf(df.z, df.z, s);
        s = fmaf(df.w, df.w, s);
    }
    #pragma unroll
    for (int o = 32; o > 0; o >>= 1) s += __shfl_down(s, o, 64);
    __shared__ float ls[4];
    if ((threadIdx.x & 63) == 0) ls[threadIdx.x >> 6] = s;
    __syncthreads();
    if (threadIdx.x == 0) part[blockIdx.x] = ls[0] + ls[1] + ls[2] + ls[3];
}

// ---------------- K7: loss (from partials) + perplexity ---------------------
__global__ __launch_bounds__(256) void finalize(
    const float* __restrict__ counts, const float* __restrict__ part,
    float* __restrict__ out)
{
    __shared__ float sh[512];
    float h = 0.f;
    for (int k = threadIdx.x; k < K_CODES; k += 256) {
        float p = counts[k] * (1.0f / N_FLAT);
        h += p * logf(p + 1e-10f);
    }
    float s = 0.f;
    for (int i = threadIdx.x; i < 1024; i += 256) s += part[i];
    sh[threadIdx.x] = h;
    sh[256 + threadIdx.x] = s;
    __syncthreads();
    #pragma unroll
    for (int st = 128; st > 0; st >>= 1) {
        if (threadIdx.x < st) {
            sh[threadIdx.x] += sh[threadIdx.x + st];
            sh[256 + threadIdx.x] += sh[256 + threadIdx.x + st];
        }
        __syncthreads();
    }
    if (threadIdx.x == 0) {
        float perp = expf(-sh[0]);
        float loss = 1.25f * (sh[256] / 4194304.0f);
        if (isnan(loss) || isinf(loss)) loss = 0.1f;
        out[OFF_LOSS] = loss;
        out[OFF_PERP] = perp;
    }
}

extern "C" void kernel_launch(void* const* d_in, const int* in_sizes, int n_in,
                              void* d_out, int out_size, void* d_ws, size_t ws_size,
                              hipStream_t stream) {
    const float* x = (const float*)d_in[0];   // [32,128,32,32] fp32 NCHW
    const float* w = (const float*)d_in[1];   // [4096,128] fp32
    float* out = (float*)d_out;
    char* ws = (char*)d_ws;

    unsigned long long* packed = (unsigned long long*)(ws + WS_PACKED);
    float* counts = (float*)(ws + WS_COUNTS);
    float* wsq    = (float*)(ws + WS_WSQ);
    float* xsq    = (float*)(ws + WS_XSQ);
    float* part   = (float*)(ws + WS_PART);
    _Float16* xhl = (_Float16*)(ws + WS_XHL);
    _Float16* whl = (_Float16*)(ws + WS_WHL);

    wsq_kernel<<<K_CODES / 4, 256, 0, stream>>>(w, wsq, counts);
    wplanes_kernel<<<K_CODES * 4 / 256, 256, 0, stream>>>(w, whl);
    xprep_kernel<<<N_FLAT / 64, 256, 0, stream>>>(x, xhl, xsq, packed);

    dim3 g2(256, 8);
    dist_argmin<<<g2, 256, 0, stream>>>(xhl, whl, wsq, xsq, packed,
                                        out + OFF_ENC);

    combine<<<N_FLAT / 256, 256, 0, stream>>>(packed, out + OFF_IDX,
                                              out + OFF_ENC, counts);

    quantize_loss<<<1024, 256, 0, stream>>>(x, w, out + OFF_IDX,
                                            out + OFF_Q, part);

    finalize<<<1, 256, 0, stream>>>(counts, part, out);
}